// Round 1
// baseline (739.167 us; speedup 1.0000x reference)
//
#include <hip/hip_runtime.h>

// 2-layer GRU (reset_after, sigmoid recurrent act, linear act, no bias) + Wout.
// B=16384, T=25, D=128. Fully fused: 256 blocks x 256 threads, each block owns
// 64 batch rows; h1/h2 live in LDS (fp16); weights live in REGISTERS as MFMA
// B-fragments for all 25 steps (384 VGPRs/wave). f16 MFMA (16x16x32), fp32 acc.
//
// Wave w (of 4) owns d-slices {2w, 2w+1} (16 cols each) of the 3*128 gate dims
// for BOTH layers, so gate combine (z, r, candidate xh + r*uh) is wave-local.
// Accumulators per (m-tile, slice): cz, cr (K=256 over [x|h]) and cxh (K=0..127,
// x part) / cuh (K=128..255, h part) kept separate because hh = xh + r*uh.

typedef _Float16 half8 __attribute__((ext_vector_type(8)));
typedef float f32x4 __attribute__((ext_vector_type(4)));

#define MFMA(a, b, c) __builtin_amdgcn_mfma_f32_16x16x32_f16((a), (b), (c), 0, 0, 0)

constexpr int T_STEPS = 25;
constexpr int D = 128;
constexpr int NG = 384;    // 3*D gate width
constexpr int BT = 64;     // batch rows per block
constexpr int SA = 264;    // row stride (fp16) of [x|h] concat buffers (256 + 8 pad)
constexpr int SH = 136;    // row stride (fp16) of h-new buffers (128 + 8 pad)

__device__ __forceinline__ float fast_sigmoid(float x) {
    return 1.0f / (1.0f + __expf(-x));
}

// One GRU layer step for this block's 64 rows.
// sAin: [64][SA] fp16, cols 0..127 = layer input, cols 128..255 = h_prev.
// sHout: [64][SH] fp16, receives h_new (cols 0..127).
// wgt[j][g][k]: B-fragments, j = slice (d0=(2w+j)*16), g = gate (z,r,h), k = K-tile.
__device__ __forceinline__ void gru_layer(const _Float16* sAin, _Float16* sHout,
                                          const half8 (&wgt)[2][3][8],
                                          int w, int l15, int quad) {
#pragma unroll
    for (int m = 0; m < 4; ++m) {
        // A-fragments for rows m*16..m*16+15, K = 0..255 (conflict-free b128 reads)
        half8 A[8];
        const _Float16* ap = sAin + (m * 16 + l15) * SA + quad * 8;
#pragma unroll
        for (int k = 0; k < 8; ++k) A[k] = *(const half8*)(ap + k * 32);
#pragma unroll
        for (int j = 0; j < 2; ++j) {
            f32x4 cz = {0.f, 0.f, 0.f, 0.f}, cr = {0.f, 0.f, 0.f, 0.f};
            f32x4 cxh = {0.f, 0.f, 0.f, 0.f}, cuh = {0.f, 0.f, 0.f, 0.f};
#pragma unroll
            for (int k = 0; k < 4; ++k) {   // x part (K 0..127)
                cz  = MFMA(A[k], wgt[j][0][k], cz);
                cr  = MFMA(A[k], wgt[j][1][k], cr);
                cxh = MFMA(A[k], wgt[j][2][k], cxh);
            }
#pragma unroll
            for (int k = 4; k < 8; ++k) {   // h part (K 128..255)
                cz  = MFMA(A[k], wgt[j][0][k], cz);
                cr  = MFMA(A[k], wgt[j][1][k], cr);
                cuh = MFMA(A[k], wgt[j][2][k], cuh);
            }
            const int d = (2 * w + j) * 16 + l15;
#pragma unroll
            for (int i = 0; i < 4; ++i) {   // C/D layout: col=lane&15, row=quad*4+i
                const int row = m * 16 + quad * 4 + i;
                const float hp = (float)sAin[row * SA + 128 + d];
                const float z = fast_sigmoid(cz[i]);
                const float r = fast_sigmoid(cr[i]);
                const float hh = cxh[i] + r * cuh[i];
                const float hn = z * hp + (1.0f - z) * hh;
                sHout[row * SH + d] = (_Float16)hn;
            }
        }
    }
}

// Copy h_new [64][SH] into dst1 cols 128.. (as next h_prev) and optionally dst2
// cols 0.. (as next layer's input).
__device__ __forceinline__ void copy_h(const _Float16* sH, _Float16* dst1,
                                       _Float16* dst2, int tid) {
    const int row = tid >> 2, seg = tid & 3;
    const _Float16* s = sH + row * SH + seg * 32;
#pragma unroll
    for (int q = 0; q < 4; ++q) {
        half8 v = *(const half8*)(s + q * 8);
        *(half8*)(dst1 + row * SA + 128 + seg * 32 + q * 8) = v;
        if (dst2) *(half8*)(dst2 + row * SA + seg * 32 + q * 8) = v;
    }
}

__global__ __launch_bounds__(256, 1) void gru2_kernel(
    const float* __restrict__ x, const float* __restrict__ W1,
    const float* __restrict__ U1, const float* __restrict__ W2,
    const float* __restrict__ U2, const float* __restrict__ Wout,
    float* __restrict__ out) {
    __shared__ _Float16 sA1[BT * SA];  // [x_t | h1]
    __shared__ _Float16 sA2[BT * SA];  // [h1_t | h2]
    __shared__ _Float16 sH1[BT * SH];
    __shared__ _Float16 sH2[BT * SH];

    const int tid = threadIdx.x;
    const int w = tid >> 6;
    const int lane = tid & 63;
    const int l15 = lane & 15;
    const int quad = lane >> 4;
    const int b0 = blockIdx.x * BT;

    // ---- one-time: load both layers' [W;U] B-fragments into registers ----
    // B-frag layout (16x16x32): lane holds B[k = quad*8 + i][n = lane&15].
    half8 wB[2][2][3][8];
#pragma unroll
    for (int l = 0; l < 2; ++l) {
        const float* Wp = l ? W2 : W1;
        const float* Up = l ? U2 : U1;
#pragma unroll
        for (int j = 0; j < 2; ++j)
#pragma unroll
            for (int g = 0; g < 3; ++g) {
                const int col = g * 128 + (2 * w + j) * 16 + l15;
#pragma unroll
                for (int k = 0; k < 8; ++k) {
                    half8 f;
#pragma unroll
                    for (int i = 0; i < 8; ++i) {
                        const int kk = k * 32 + quad * 8 + i;
                        const float v = (kk < 128) ? Wp[kk * NG + col]
                                                   : Up[(kk - 128) * NG + col];
                        f[i] = (_Float16)v;
                    }
                    wB[l][j][g][k] = f;
                }
            }
    }

    // zero h states (and pads, harmless)
    for (int i = tid; i < BT * SA; i += 256) {
        sA1[i] = (_Float16)0.f;
        sA2[i] = (_Float16)0.f;
    }
    __syncthreads();

    const int rowS = tid >> 2, segS = tid & 3;
#pragma unroll 1
    for (int t = 0; t < T_STEPS; ++t) {
        // stage x_t -> sA1 cols 0..127 (fp32 -> fp16)
        {
            const float* xp = x + ((size_t)(b0 + rowS) * T_STEPS + t) * D + segS * 32;
            _Float16* dst = sA1 + rowS * SA + segS * 32;
#pragma unroll
            for (int q = 0; q < 4; ++q) {
                const float4 v0 = ((const float4*)xp)[q * 2];
                const float4 v1 = ((const float4*)xp)[q * 2 + 1];
                half8 h;
                h[0] = (_Float16)v0.x; h[1] = (_Float16)v0.y;
                h[2] = (_Float16)v0.z; h[3] = (_Float16)v0.w;
                h[4] = (_Float16)v1.x; h[5] = (_Float16)v1.y;
                h[6] = (_Float16)v1.z; h[7] = (_Float16)v1.w;
                *(half8*)(dst + q * 8) = h;
            }
        }
        __syncthreads();                       // x_t + prev h visible
        gru_layer(sA1, sH1, wB[0], w, l15, quad);
        __syncthreads();                       // sH1 done; sA1 reads done
        copy_h(sH1, sA1, sA2, tid);            // h1 -> sA1[:,128:], sA2[:,0:128]
        __syncthreads();                       // sA2 input ready
        gru_layer(sA2, sH2, wB[1], w, l15, quad);
        __syncthreads();                       // sH2 done; sA2 reads done
        copy_h(sH2, sA2, nullptr, tid);        // h2 -> sA2[:,128:]
        // no barrier needed: next reads of sA2 h-region are 3 barriers away
    }

    // ---- epilogue: out = h2 @ Wout via MFMA ----
    half8 wO[2][4];
#pragma unroll
    for (int j = 0; j < 2; ++j) {
        const int col = (2 * w + j) * 16 + l15;
#pragma unroll
        for (int k = 0; k < 4; ++k) {
            half8 f;
#pragma unroll
            for (int i = 0; i < 8; ++i)
                f[i] = (_Float16)Wout[(k * 32 + quad * 8 + i) * D + col];
            wO[j][k] = f;
        }
    }
#pragma unroll
    for (int m = 0; m < 4; ++m) {
        half8 A[4];
        const _Float16* ap = sH2 + (m * 16 + l15) * SH + quad * 8;
#pragma unroll
        for (int k = 0; k < 4; ++k) A[k] = *(const half8*)(ap + k * 32);
#pragma unroll
        for (int j = 0; j < 2; ++j) {
            f32x4 acc = {0.f, 0.f, 0.f, 0.f};
#pragma unroll
            for (int k = 0; k < 4; ++k) acc = MFMA(A[k], wO[j][k], acc);
            const int col = (2 * w + j) * 16 + l15;
#pragma unroll
            for (int i = 0; i < 4; ++i)
                out[(size_t)(b0 + m * 16 + quad * 4 + i) * D + col] = acc[i];
        }
    }
}

extern "C" void kernel_launch(void* const* d_in, const int* in_sizes, int n_in,
                              void* d_out, int out_size, void* d_ws, size_t ws_size,
                              hipStream_t stream) {
    const float* x    = (const float*)d_in[0];
    const float* W1   = (const float*)d_in[1];
    const float* U1   = (const float*)d_in[2];
    const float* W2   = (const float*)d_in[3];
    const float* U2   = (const float*)d_in[4];
    const float* Wout = (const float*)d_in[5];
    gru2_kernel<<<dim3(16384 / BT), dim3(256), 0, stream>>>(
        x, W1, U1, W2, U2, Wout, (float*)d_out);
}

// Round 2
// 542.066 us; speedup vs baseline: 1.3636x; 1.3636x over previous
//
#include <hip/hip_runtime.h>

// 2-layer GRU (reset_after, sigmoid gates, linear act, no bias) + Wout.
// B=16384, T=25, D=128. 256 blocks x 512 threads; block owns 64 batch rows.
// Layer-pipelined waves: w0-3 = layer1 @ step i, w4-7 = layer2 @ step i-1.
// Each wave: ONE layer's [W;U] B-fragments in 192 VGPRs, h_prev carried in
// registers (16), x staged by global_load_lds into padded f32 LDS (no regs).
// One barrier per iteration; 26 iterations.

typedef _Float16 half8 __attribute__((ext_vector_type(8)));
typedef float f32x4 __attribute__((ext_vector_type(4)));

#define MFMA(a, b, c) __builtin_amdgcn_mfma_f32_16x16x32_f16((a), (b), (c), 0, 0, 0)

constexpr int T_STEPS = 25;
constexpr int D = 128;
constexpr int NG = 384;   // 3*D
constexpr int BT = 64;    // batch rows per block
constexpr int SH = 136;   // f16 row stride of H buffers (128 + 8 pad)
constexpr int SX = 132;   // f32 row stride of X buffers (128 + 4 pad)

typedef const __attribute__((address_space(1))) unsigned int guint;
typedef __attribute__((address_space(3))) unsigned int luint;

__device__ __forceinline__ void load_lds4(const float* g, float* l) {
    // one dword per lane, LDS dest = wave-uniform(l) + lane*4
    __builtin_amdgcn_global_load_lds((guint*)(uintptr_t)g, (luint*)l, 4, 0, 0);
}

__device__ __forceinline__ float sigm(float v) { return 1.0f / (1.0f + __expf(-v)); }

__global__ __launch_bounds__(512, 2) void gru2_kernel(
    const float* __restrict__ x, const float* __restrict__ W1,
    const float* __restrict__ U1, const float* __restrict__ W2,
    const float* __restrict__ U2, const float* __restrict__ Wout,
    float* __restrict__ out) {
    __shared__ float    X[2][BT * SX];   // x_t staging, f32, double-buffered (67.6 KB)
    __shared__ _Float16 H1[2][BT * SH];  // h1 state, double-buffered (34.8 KB)
    __shared__ _Float16 H2[2][BT * SH];  // h2 state, double-buffered (34.8 KB)

    const int tid = threadIdx.x;
    const int w = tid >> 6, lane = tid & 63, l15 = lane & 15, quad = lane >> 4;
    const bool L2w = (w >= 4);
    const int wl = w & 3;
    const int b0 = blockIdx.x * BT;

    // ---- one-time: this wave's layer's [W;U] B-fragments (192 VGPRs) ----
    // B-frag (16x16x32): lane holds B[k = quad*8 + e][n = l15]. k-tiles 0..3 = W
    // rows 0..127 (input), 4..7 = U rows 0..127 (state).
    half8 wg[2][3][8];  // [col-slice j][gate][ktile]
    {
        const float* Wp = L2w ? W2 : W1;
        const float* Up = L2w ? U2 : U1;
#pragma unroll
        for (int j = 0; j < 2; ++j) {
            const int col0 = (2 * wl + j) * 16 + l15;
#pragma unroll
            for (int g = 0; g < 3; ++g) {
                const int c = g * 128 + col0;
#pragma unroll
                for (int k = 0; k < 8; ++k) {
                    const float* src = (k < 4 ? Wp : Up) + (size_t)((k & 3) * 32 + quad * 8) * NG + c;
                    half8 f;
#pragma unroll
                    for (int e = 0; e < 8; ++e) f[e] = (_Float16)src[(size_t)e * NG];
                    wg[j][g][k] = f;
                }
            }
        }
    }

    // zero initial states: L1 reads H1[0] at iter 0; L2 reads H2[1] at iter 1
    for (int idx = tid; idx < BT * SH; idx += 512) {
        H1[0][idx] = (_Float16)0.f;
        H2[1][idx] = (_Float16)0.f;
    }

    // prefetch x(t=0) into X[0]: 128 half-row DMAs per block, 16 per wave
#pragma unroll
    for (int r8 = 0; r8 < 16; ++r8) {
        const int idx = w * 16 + r8, row = idx >> 1, half = (idx & 1) * 64;
        load_lds4(x + ((size_t)(b0 + row) * T_STEPS + 0) * D + half + lane,
                  &X[0][row * SX + half]);
    }

    half8 hpv[2][2] = {};  // h_prev carry, [j][reg of 8]: element el=m*4+i

    __syncthreads();  // drains DMA (compiler emits vmcnt(0) before s_barrier)

#pragma unroll 1
    for (int it = 0; it <= T_STEPS; ++it) {
        const int p = it & 1, q = p ^ 1;
        // issue DMA for x(it+1) -> X[q]; overlaps this iteration's compute
        if (it + 1 < T_STEPS) {
#pragma unroll
            for (int r8 = 0; r8 < 16; ++r8) {
                const int idx = w * 16 + r8, row = idx >> 1, half = (idx & 1) * 64;
                load_lds4(x + ((size_t)(b0 + row) * T_STEPS + (it + 1)) * D + half + lane,
                          &X[q][row * SX + half]);
            }
        }
        const bool active = L2w ? (it >= 1) : (it < T_STEPS);
        if (active) {
            const _Float16* Hst = L2w ? H2[p] : H1[p];  // own state (h_prev source for MFMA)
            _Float16* Hout      = L2w ? H2[q] : H1[q];  // own state dest
            const _Float16* Hin = H1[p];                // layer-2 input = h1
            const float* Xin    = X[p];                 // layer-1 input = x_t
#pragma unroll
            for (int m = 0; m < 4; ++m) {
                const int arow = m * 16 + l15;
                half8 Ax[4], As[4];
                if (!L2w) {
                    const float* ap = Xin + arow * SX + quad * 8;
#pragma unroll
                    for (int k = 0; k < 4; ++k) {
                        const float4 v0 = *(const float4*)(ap + k * 32);
                        const float4 v1 = *(const float4*)(ap + k * 32 + 4);
                        half8 f;
                        f[0] = (_Float16)v0.x; f[1] = (_Float16)v0.y;
                        f[2] = (_Float16)v0.z; f[3] = (_Float16)v0.w;
                        f[4] = (_Float16)v1.x; f[5] = (_Float16)v1.y;
                        f[6] = (_Float16)v1.z; f[7] = (_Float16)v1.w;
                        Ax[k] = f;
                    }
                } else {
                    const _Float16* ap = Hin + arow * SH + quad * 8;
#pragma unroll
                    for (int k = 0; k < 4; ++k) Ax[k] = *(const half8*)(ap + k * 32);
                }
                {
                    const _Float16* ap = Hst + arow * SH + quad * 8;
#pragma unroll
                    for (int k = 0; k < 4; ++k) As[k] = *(const half8*)(ap + k * 32);
                }
#pragma unroll
                for (int j = 0; j < 2; ++j) {
                    f32x4 cz = {0.f, 0.f, 0.f, 0.f}, cr = {0.f, 0.f, 0.f, 0.f};
                    f32x4 cxh = {0.f, 0.f, 0.f, 0.f}, cuh = {0.f, 0.f, 0.f, 0.f};
#pragma unroll
                    for (int k = 0; k < 4; ++k) {  // input part (W)
                        cz  = MFMA(Ax[k], wg[j][0][k], cz);
                        cr  = MFMA(Ax[k], wg[j][1][k], cr);
                        cxh = MFMA(Ax[k], wg[j][2][k], cxh);
                    }
#pragma unroll
                    for (int k = 0; k < 4; ++k) {  // state part (U)
                        cz  = MFMA(As[k], wg[j][0][4 + k], cz);
                        cr  = MFMA(As[k], wg[j][1][4 + k], cr);
                        cuh = MFMA(As[k], wg[j][2][4 + k], cuh);
                    }
                    const int d = (2 * wl + j) * 16 + l15;
#pragma unroll
                    for (int i2 = 0; i2 < 4; ++i2) {  // C/D: col=l15, row=quad*4+i2
                        const int el = m * 4 + i2;
                        const float hp = (float)hpv[j][el >> 3][el & 7];
                        const float z = sigm(cz[i2]);
                        const float r = sigm(cr[i2]);
                        const float hh = cxh[i2] + r * cuh[i2];
                        const float hn = hh + z * (hp - hh);
                        const _Float16 h16 = (_Float16)hn;
                        hpv[j][el >> 3][el & 7] = h16;
                        Hout[(m * 16 + quad * 4 + i2) * SH + d] = h16;
                    }
                }
            }
        }
        __syncthreads();
    }

    // ---- epilogue: out = h2(T-1) @ Wout; h2 is in H2[0] (q at it=25) ----
    half8 wO[4];
    {
        const int col = w * 16 + l15;
#pragma unroll
        for (int k = 0; k < 4; ++k) {
            half8 f;
#pragma unroll
            for (int e = 0; e < 8; ++e)
                f[e] = (_Float16)Wout[(size_t)(k * 32 + quad * 8 + e) * D + col];
            wO[k] = f;
        }
    }
#pragma unroll
    for (int m = 0; m < 4; ++m) {
        half8 A[4];
        const _Float16* ap = H2[0] + (m * 16 + l15) * SH + quad * 8;
#pragma unroll
        for (int k = 0; k < 4; ++k) A[k] = *(const half8*)(ap + k * 32);
        f32x4 acc = {0.f, 0.f, 0.f, 0.f};
#pragma unroll
        for (int k = 0; k < 4; ++k) acc = MFMA(A[k], wO[k], acc);
        const int col = w * 16 + l15;
#pragma unroll
        for (int i2 = 0; i2 < 4; ++i2)
            out[(size_t)(b0 + m * 16 + quad * 4 + i2) * D + col] = acc[i2];
    }
}

extern "C" void kernel_launch(void* const* d_in, const int* in_sizes, int n_in,
                              void* d_out, int out_size, void* d_ws, size_t ws_size,
                              hipStream_t stream) {
    const float* x    = (const float*)d_in[0];
    const float* W1   = (const float*)d_in[1];
    const float* U1   = (const float*)d_in[2];
    const float* W2   = (const float*)d_in[3];
    const float* U2   = (const float*)d_in[4];
    const float* Wout = (const float*)d_in[5];
    gru2_kernel<<<dim3(16384 / BT), dim3(512), 0, stream>>>(
        x, W1, U1, W2, U2, Wout, (float*)d_out);
}

// Round 4
// 536.882 us; speedup vs baseline: 1.3768x; 1.0097x over previous
//
#include <hip/hip_runtime.h>

// 2-layer GRU (reset_after, sigmoid gates, linear act, no bias) + Wout.
// B=16384, T=25, D=128. 256 blocks x 512 threads; block owns 64 batch rows.
// Layer-pipelined waves: w0-3 = layer1 @ step i, w4-7 = layer2 @ step i-1.
// Each wave: ONE layer's [W;U] B-fragments = 48 frags = 192 regs, PINNED INTO
// AGPRS via asm "+a" (rounds 1-2 proved the allocator scratch-spills them
// otherwise). VGPR side: A-frags 32 + acc 16 + h-carry 8 + temps ~= 64.
// Per-SIMD unified file: 2 waves x 256 = 512 exactly. One barrier/iter.

typedef _Float16 half8 __attribute__((ext_vector_type(8)));
typedef __fp16  fp16x2 __attribute__((ext_vector_type(2)));   // cvt_pkrtz result type
typedef float f32x4 __attribute__((ext_vector_type(4)));

#define MFMA(a, b, c) __builtin_amdgcn_mfma_f32_16x16x32_f16((a), (b), (c), 0, 0, 0)

constexpr int T_STEPS = 25;
constexpr int D = 128;
constexpr int NG = 384;   // 3*D
constexpr int BT = 64;    // batch rows per block
constexpr int SH = 136;   // f16 row stride of H buffers: 272 B == 16 mod 128 -> conflict-free b128
constexpr int SX = 132;   // f32 row stride of X buffers: 528 B == 16 mod 128 -> conflict-free b128

typedef const __attribute__((address_space(1))) unsigned int guint;
typedef __attribute__((address_space(3))) unsigned int luint;

__device__ __forceinline__ void load_lds4(const float* g, float* l) {
    // one dword per lane, LDS dest = wave-uniform base + lane*4
    __builtin_amdgcn_global_load_lds((guint*)(uintptr_t)g, (luint*)l, 4, 0, 0);
}

__device__ __forceinline__ float sigm(float v) { return 1.0f / (1.0f + __expf(-v)); }

__global__ __launch_bounds__(512, 2) void gru2_kernel(
    const float* __restrict__ x, const float* __restrict__ W1,
    const float* __restrict__ U1, const float* __restrict__ W2,
    const float* __restrict__ U2, const float* __restrict__ Wout,
    float* __restrict__ out) {
    __shared__ float    X[2][BT * SX];   // x_t staging, f32, double-buffered (67.6 KB)
    __shared__ _Float16 H1[2][BT * SH];  // h1 state, double-buffered (34.8 KB)
    __shared__ _Float16 H2[2][BT * SH];  // h2 state, double-buffered (34.8 KB)

    const int tid = threadIdx.x;
    const int w = tid >> 6, lane = tid & 63, l15 = lane & 15, quad = lane >> 4;
    const bool L2w = (w >= 4);
    const int wl = w & 3;
    const int b0 = blockIdx.x * BT;

    // ---- one-time: this wave's layer's [W;U] B-fragments, then PIN to AGPR ----
    // B-frag (16x16x32): lane holds B[k = quad*8 + e][n = l15]. k-tiles 0..3 = W
    // rows (input part), 4..7 = U rows (state part).
    half8 wg[2][3][8];  // [col-slice j][gate][ktile]
    {
        const float* Wp = L2w ? W2 : W1;
        const float* Up = L2w ? U2 : U1;
#pragma unroll
        for (int j = 0; j < 2; ++j) {
            const int col0 = (2 * wl + j) * 16 + l15;
#pragma unroll
            for (int g = 0; g < 3; ++g) {
                const int c = g * 128 + col0;
#pragma unroll
                for (int k = 0; k < 8; ++k) {
                    const float* src = (k < 4 ? Wp : Up) + (size_t)((k & 3) * 32 + quad * 8) * NG + c;
                    half8 f;
#pragma unroll
                    for (int e = 0; e < 8; ++e) f[e] = (_Float16)src[(size_t)e * NG];
                    wg[j][g][k] = f;
                }
            }
        }
    }
    // Park all 48 weight fragments in AGPRs (192 AGPRs) so the allocator cannot
    // scratch-spill them. MFMA reads B directly from AGPR on gfx950.
#pragma unroll
    for (int j = 0; j < 2; ++j)
#pragma unroll
        for (int g = 0; g < 3; ++g)
#pragma unroll
            for (int k = 0; k < 8; ++k)
                asm volatile("" : "+a"(wg[j][g][k]));

    // zero initial states: L1 reads H1[0] at iter 0; L2 reads H2[1] at iter 1
    for (int idx = tid; idx < BT * SH; idx += 512) {
        H1[0][idx] = (_Float16)0.f;
        H2[1][idx] = (_Float16)0.f;
    }

    // prefetch x(t=0) into X[0]: 128 half-row DMAs per block, 16 per wave
#pragma unroll
    for (int r8 = 0; r8 < 16; ++r8) {
        const int idx = w * 16 + r8, row = idx >> 1, half = (idx & 1) * 64;
        load_lds4(x + ((size_t)(b0 + row) * T_STEPS + 0) * D + half + lane,
                  &X[0][row * SX + half]);
    }

    half8 hpv[2][2] = {};  // h_prev carry, [j][reg of 8]: element el = m*4+i2

    __syncthreads();  // drains DMA (compiler emits vmcnt(0) before s_barrier)

#pragma unroll 1
    for (int it = 0; it <= T_STEPS; ++it) {
        const int p = it & 1, q = p ^ 1;
        // issue DMA for x(it+1) -> X[q]; overlaps this iteration's compute
        if (it + 1 < T_STEPS) {
#pragma unroll
            for (int r8 = 0; r8 < 16; ++r8) {
                const int idx = w * 16 + r8, row = idx >> 1, half = (idx & 1) * 64;
                load_lds4(x + ((size_t)(b0 + row) * T_STEPS + (it + 1)) * D + half + lane,
                          &X[q][row * SX + half]);
            }
        }
        const bool active = L2w ? (it >= 1) : (it < T_STEPS);
        if (active) {
            const _Float16* Hst = L2w ? H2[p] : H1[p];  // own state (h_prev, MFMA operand)
            _Float16* Hout      = L2w ? H2[q] : H1[q];  // own state dest
            const _Float16* Hin = H1[p];                // layer-2 input = h1
            const float* Xin    = X[p];                 // layer-1 input = x_t
#pragma unroll
            for (int m = 0; m < 4; ++m) {
                const int arow = m * 16 + l15;
                half8 Ax[4], As[4];
                if (!L2w) {
                    const float* ap = Xin + arow * SX + quad * 8;
#pragma unroll
                    for (int k = 0; k < 4; ++k) {
                        const float4 v0 = *(const float4*)(ap + k * 32);
                        const float4 v1 = *(const float4*)(ap + k * 32 + 4);
                        union { fp16x2 h2[4]; half8 h8; } u;
                        u.h2[0] = __builtin_amdgcn_cvt_pkrtz(v0.x, v0.y);
                        u.h2[1] = __builtin_amdgcn_cvt_pkrtz(v0.z, v0.w);
                        u.h2[2] = __builtin_amdgcn_cvt_pkrtz(v1.x, v1.y);
                        u.h2[3] = __builtin_amdgcn_cvt_pkrtz(v1.z, v1.w);
                        Ax[k] = u.h8;
                    }
                } else {
                    const _Float16* ap = Hin + arow * SH + quad * 8;
#pragma unroll
                    for (int k = 0; k < 4; ++k) Ax[k] = *(const half8*)(ap + k * 32);
                }
                {
                    const _Float16* ap = Hst + arow * SH + quad * 8;
#pragma unroll
                    for (int k = 0; k < 4; ++k) As[k] = *(const half8*)(ap + k * 32);
                }
#pragma unroll
                for (int j = 0; j < 2; ++j) {
                    f32x4 cz = {0.f, 0.f, 0.f, 0.f}, cr = {0.f, 0.f, 0.f, 0.f};
                    f32x4 cxh = {0.f, 0.f, 0.f, 0.f}, cuh = {0.f, 0.f, 0.f, 0.f};
#pragma unroll
                    for (int k = 0; k < 4; ++k) {  // input part (W)
                        cz  = MFMA(Ax[k], wg[j][0][k], cz);
                        cr  = MFMA(Ax[k], wg[j][1][k], cr);
                        cxh = MFMA(Ax[k], wg[j][2][k], cxh);
                    }
#pragma unroll
                    for (int k = 0; k < 4; ++k) {  // state part (U)
                        cz  = MFMA(As[k], wg[j][0][4 + k], cz);
                        cr  = MFMA(As[k], wg[j][1][4 + k], cr);
                        cuh = MFMA(As[k], wg[j][2][4 + k], cuh);
                    }
                    const int d = (2 * wl + j) * 16 + l15;
#pragma unroll
                    for (int i2 = 0; i2 < 4; ++i2) {  // C/D: col=l15, row=quad*4+i2
                        const int el = m * 4 + i2;
                        const float hp = (float)hpv[j][el >> 3][el & 7];
                        const float z = sigm(cz[i2]);
                        const float r = sigm(cr[i2]);
                        const float hh = cxh[i2] + r * cuh[i2];
                        const float hn = hh + z * (hp - hh);
                        const _Float16 h16 = (_Float16)hn;
                        hpv[j][el >> 3][el & 7] = h16;
                        Hout[(m * 16 + quad * 4 + i2) * SH + d] = h16;
                    }
                }
            }
        }
        __syncthreads();
    }

    // ---- epilogue: out = h2(T-1) @ Wout; h2 is in H2[0] (q at it=25) ----
    half8 wO[4];
    {
        const int col = w * 16 + l15;
#pragma unroll
        for (int k = 0; k < 4; ++k) {
            half8 f;
#pragma unroll
            for (int e = 0; e < 8; ++e)
                f[e] = (_Float16)Wout[(size_t)(k * 32 + quad * 8 + e) * D + col];
            wO[k] = f;
        }
    }
#pragma unroll
    for (int m = 0; m < 4; ++m) {
        half8 A[4];
        const _Float16* ap = H2[0] + (m * 16 + l15) * SH + quad * 8;
#pragma unroll
        for (int k = 0; k < 4; ++k) A[k] = *(const half8*)(ap + k * 32);
        f32x4 acc = {0.f, 0.f, 0.f, 0.f};
#pragma unroll
        for (int k = 0; k < 4; ++k) acc = MFMA(A[k], wO[k], acc);
        const int col = w * 16 + l15;
#pragma unroll
        for (int i2 = 0; i2 < 4; ++i2)
            out[(size_t)(b0 + m * 16 + quad * 4 + i2) * D + col] = acc[i2];
    }
}

extern "C" void kernel_launch(void* const* d_in, const int* in_sizes, int n_in,
                              void* d_out, int out_size, void* d_ws, size_t ws_size,
                              hipStream_t stream) {
    const float* x    = (const float*)d_in[0];
    const float* W1   = (const float*)d_in[1];
    const float* U1   = (const float*)d_in[2];
    const float* W2   = (const float*)d_in[3];
    const float* U2   = (const float*)d_in[4];
    const float* Wout = (const float*)d_in[5];
    gru2_kernel<<<dim3(16384 / BT), dim3(512), 0, stream>>>(
        x, W1, U1, W2, U2, Wout, (float*)d_out);
}

// Round 5
// 514.412 us; speedup vs baseline: 1.4369x; 1.0437x over previous
//
#include <hip/hip_runtime.h>

// 2-layer GRU (reset_after, sigmoid gates, linear act, no bias) + Wout.
// B=16384, T=25, D=128. 256 blocks x 1024 threads (16 waves); block owns 64
// batch rows. Waves 0-7 = layer1 @ step it, waves 8-15 = layer2 @ step it-1.
// Each wave owns ONE 16-col d-slice across all 3 gates: weights = 24 frags =
// 96 VGPRs (fits the 128-reg/wave budget at 4 waves/SIMD — rounds 1-4 proved
// 192 regs/wave forces spill/copy storms). A-frags streamed k-by-k, h_prev
// read from LDS (no carry regs). One barrier per iteration; 26 iterations.

typedef _Float16 half8 __attribute__((ext_vector_type(8)));
typedef __fp16  fp16x2 __attribute__((ext_vector_type(2)));   // cvt_pkrtz result
typedef float f32x4 __attribute__((ext_vector_type(4)));

#define MFMA(a, b, c) __builtin_amdgcn_mfma_f32_16x16x32_f16((a), (b), (c), 0, 0, 0)

constexpr int T_STEPS = 25;
constexpr int D = 128;
constexpr int NG = 384;   // 3*D
constexpr int BT = 64;    // batch rows per block
constexpr int SH = 136;   // f16 row stride of H buffers: 272 B == 16 mod 128 -> conflict-free b128
constexpr int SX = 132;   // f32 row stride of X buffers: 528 B == 16 mod 128 -> conflict-free b128

typedef const __attribute__((address_space(1))) unsigned int guint;
typedef __attribute__((address_space(3))) unsigned int luint;

__device__ __forceinline__ void load_lds4(const float* g, float* l) {
    // one dword per lane, LDS dest = wave-uniform base + lane*4
    __builtin_amdgcn_global_load_lds((guint*)(uintptr_t)g, (luint*)l, 4, 0, 0);
}

__device__ __forceinline__ float sigm(float v) {
    return __builtin_amdgcn_rcpf(1.0f + __expf(-v));
}

__global__ __launch_bounds__(1024, 4) void gru2_kernel(
    const float* __restrict__ x, const float* __restrict__ W1,
    const float* __restrict__ U1, const float* __restrict__ W2,
    const float* __restrict__ U2, const float* __restrict__ Wout,
    float* __restrict__ out) {
    __shared__ float    X[2][BT * SX];   // x_t staging, f32, double-buffered (67.6 KB)
    __shared__ _Float16 H1[2][BT * SH];  // h1 state, double-buffered (34.8 KB)
    __shared__ _Float16 H2[2][BT * SH];  // h2 state, double-buffered (34.8 KB)

    const int tid = threadIdx.x;
    const int w = tid >> 6, lane = tid & 63, l15 = lane & 15, quad = lane >> 4;
    const int layer = w >> 3;       // 0: layer1 waves, 1: layer2 waves
    const int d0 = (w & 7) * 16;    // this wave's d-slice (8 waves x 16 = 128)
    const int b0 = blockIdx.x * BT;

    // ---- one-time: this wave's [W;U] B-fragments: 3 gates x 8 ktiles = 96 regs ----
    // B-frag (16x16x32): lane holds B[k = quad*8 + e][n = l15]. k-tiles 0..3 = W
    // rows (input part), 4..7 = U rows (state part).
    half8 wg[3][8];
    {
        const float* Wp = layer ? W2 : W1;
        const float* Up = layer ? U2 : U1;
#pragma unroll
        for (int g = 0; g < 3; ++g) {
            const int c = g * 128 + d0 + l15;
#pragma unroll
            for (int k = 0; k < 8; ++k) {
                const float* src = (k < 4 ? Wp : Up) + (size_t)((k & 3) * 32 + quad * 8) * NG + c;
                half8 f;
#pragma unroll
                for (int e = 0; e < 8; ++e) f[e] = (_Float16)src[(size_t)e * NG];
                wg[g][k] = f;
            }
        }
    }

    // zero initial states: L1 reads H1[0] at iter 0; L2 reads H2[1] at iter 1
    for (int idx = tid; idx < BT * SH; idx += 1024) {
        H1[0][idx] = (_Float16)0.f;
        H2[1][idx] = (_Float16)0.f;
    }

    // prefetch x(t=0) into X[0]: 128 half-row DMAs per block, 8 per wave
#pragma unroll
    for (int r8 = 0; r8 < 8; ++r8) {
        const int idx = w * 8 + r8, row = idx >> 1, hf = (idx & 1) * 64;
        load_lds4(x + ((size_t)(b0 + row) * T_STEPS + 0) * D + hf + lane,
                  &X[0][row * SX + hf]);
    }

    __syncthreads();  // drains DMA (compiler emits vmcnt(0) before s_barrier)

#pragma unroll 1
    for (int it = 0; it <= T_STEPS; ++it) {
        const int p = it & 1, q = p ^ 1;
        // issue DMA for x(it+1) -> X[q]; overlaps this iteration's compute
        if (it + 1 < T_STEPS) {
#pragma unroll
            for (int r8 = 0; r8 < 8; ++r8) {
                const int idx = w * 8 + r8, row = idx >> 1, hf = (idx & 1) * 64;
                load_lds4(x + ((size_t)(b0 + row) * T_STEPS + (it + 1)) * D + hf + lane,
                          &X[q][row * SX + hf]);
            }
        }
        const bool active = layer ? (it >= 1) : (it < T_STEPS);
        if (active) {
            const _Float16* Hst = layer ? H2[p] : H1[p];  // own state (h_prev)
            _Float16* Hout      = layer ? H2[q] : H1[q];  // own state dest
            const _Float16* Hin = H1[p];                  // layer-2 input = h1
            const float* Xin    = X[p];                   // layer-1 input = x_t
#pragma unroll
            for (int m = 0; m < 4; ++m) {
                const int arow = m * 16 + l15;
                f32x4 cz = {0.f, 0.f, 0.f, 0.f}, cr = {0.f, 0.f, 0.f, 0.f};
                f32x4 cxh = {0.f, 0.f, 0.f, 0.f}, cuh = {0.f, 0.f, 0.f, 0.f};
#pragma unroll
                for (int k = 0; k < 4; ++k) {  // input part (W): x_t or h1
                    half8 A;
                    if (!layer) {
                        const float* ap = Xin + arow * SX + quad * 8 + k * 32;
                        const float4 v0 = *(const float4*)(ap);
                        const float4 v1 = *(const float4*)(ap + 4);
                        union { fp16x2 h2[4]; half8 h8; } u;
                        u.h2[0] = __builtin_amdgcn_cvt_pkrtz(v0.x, v0.y);
                        u.h2[1] = __builtin_amdgcn_cvt_pkrtz(v0.z, v0.w);
                        u.h2[2] = __builtin_amdgcn_cvt_pkrtz(v1.x, v1.y);
                        u.h2[3] = __builtin_amdgcn_cvt_pkrtz(v1.z, v1.w);
                        A = u.h8;
                    } else {
                        A = *(const half8*)(Hin + arow * SH + quad * 8 + k * 32);
                    }
                    cz  = MFMA(A, wg[0][k], cz);
                    cr  = MFMA(A, wg[1][k], cr);
                    cxh = MFMA(A, wg[2][k], cxh);
                }
#pragma unroll
                for (int k = 0; k < 4; ++k) {  // state part (U): h_prev
                    const half8 A = *(const half8*)(Hst + arow * SH + quad * 8 + k * 32);
                    cz  = MFMA(A, wg[0][4 + k], cz);
                    cr  = MFMA(A, wg[1][4 + k], cr);
                    cuh = MFMA(A, wg[2][4 + k], cuh);
                }
#pragma unroll
                for (int i2 = 0; i2 < 4; ++i2) {  // C/D: col=l15, row=quad*4+i2
                    const int row = m * 16 + quad * 4 + i2;
                    const float hp = (float)Hst[row * SH + d0 + l15];
                    const float z = sigm(cz[i2]);
                    const float r = sigm(cr[i2]);
                    const float hh = cxh[i2] + r * cuh[i2];
                    const float hn = hh + z * (hp - hh);
                    Hout[row * SH + d0 + l15] = (_Float16)hn;
                }
            }
        }
        __syncthreads();
    }

    // ---- epilogue: out = h2(T-1) @ Wout; h2 is in H2[0] (q at it=25) ----
    // waves 8-15 only (8 waves x 16 cols = 128)
    if (layer) {
        const int col = d0 + l15;
        half8 wO[4];
#pragma unroll
        for (int k = 0; k < 4; ++k) {
            half8 f;
#pragma unroll
            for (int e = 0; e < 8; ++e)
                f[e] = (_Float16)Wout[(size_t)(k * 32 + quad * 8 + e) * D + col];
            wO[k] = f;
        }
#pragma unroll
        for (int m = 0; m < 4; ++m) {
            const _Float16* ap = H2[0] + (m * 16 + l15) * SH + quad * 8;
            f32x4 acc = {0.f, 0.f, 0.f, 0.f};
#pragma unroll
            for (int k = 0; k < 4; ++k) {
                const half8 A = *(const half8*)(ap + k * 32);
                acc = MFMA(A, wO[k], acc);
            }
#pragma unroll
            for (int i2 = 0; i2 < 4; ++i2)
                out[(size_t)(b0 + m * 16 + quad * 4 + i2) * D + col] = acc[i2];
        }
    }
}

extern "C" void kernel_launch(void* const* d_in, const int* in_sizes, int n_in,
                              void* d_out, int out_size, void* d_ws, size_t ws_size,
                              hipStream_t stream) {
    const float* x    = (const float*)d_in[0];
    const float* W1   = (const float*)d_in[1];
    const float* U1   = (const float*)d_in[2];
    const float* W2   = (const float*)d_in[3];
    const float* U2   = (const float*)d_in[4];
    const float* Wout = (const float*)d_in[5];
    gru2_kernel<<<dim3(16384 / BT), dim3(1024), 0, stream>>>(
        x, W1, U1, W2, U2, Wout, (float*)d_out);
}